// Round 10
// baseline (123.442 us; speedup 1.0000x reference)
//
#include <hip/hip_runtime.h>

#define SS 730
#define GG 4000
#define LENF 15
#define PD 10          // prefetch depth (steps); 730 % 10 == 0
#define GPAD 4032      // 63 waves per instance -> no wave mixes models
#define TT 10          // route time-tile; 730 % 10 == 0
#define QN ((size_t)SS * GG)
#define QNI ((int)(SS * GG))

// ---------------------------------------------------------------------------
// Scan kernel, round-10: STAGE-PIPELINED recurrences.
// One thread per (g, m, model); inst = tid/GPAD: 0,1 HBV; 2,3 EXP.
// HBV is a cascade (sp,mw) -> rt -> (sm) -> rech/exc -> (suz,slz) -> q.
// At loop iter i we compute S1(step i), S2(step i-1), S3(step i-2): the
// three stages only read PREVIOUS-iter pipeline registers, so the per-iter
// DAG is three short independent chains (max ~45 cyc) instead of one
// ~140-cyc serial chain -- in-order issue can interleave them.
// Chunk 0 is peeled to warm the pipeline exactly (no state perturbation);
// 2 drain iters finish q(SS-2), q(SS-1). Slices stay dense (stride SS*GG).
// ---------------------------------------------------------------------------
template<bool STORE4>
__global__ __launch_bounds__(64, 1) void hydro_scan(const float* __restrict__ x,
                                                    const float* __restrict__ raw,
                                                    float* __restrict__ qsim) {
    int tid = blockIdx.x * 64 + threadIdx.x;
    int g = tid % GPAD;
    int inst = tid / GPAD;
    if (g >= GG) return;
    int m = inst & 1;
    const float* pr = raw + (size_t)g * 38 + m;   // pr[2*i] = raw[g, i*2+m]

    int xoff = g * 3;
    int qoff = g + (STORE4 ? inst * QNI : 0);     // first store lands row 0

    // prefetch pipeline: steps 0..PD-1
    float pb[PD], tb[PD], eb[PD];
#pragma unroll
    for (int j = 0; j < PD; ++j) {
        pb[j] = x[xoff]; tb[j] = x[xoff + 1]; eb[j] = x[xoff + 2];
        xoff += 3 * GG;
    }

    if (inst < 2) {
        // ---- HBV parameters (descale + derived constants) ----
        float beta  = 1.0f   + pr[0]  * 5.0f;
        float fc    = 50.0f  + pr[2]  * 950.0f;
        float k0    = 0.05f  + pr[4]  * 0.85f;
        float k1    = 0.01f  + pr[6]  * 0.49f;
        float k2    = 0.001f + pr[8]  * 0.199f;
        float lp    = 0.2f   + pr[10] * 0.8f;
        float perc  =          pr[12] * 10.0f;
        float uzl   =          pr[14] * 100.0f;
        float tt    = -2.5f  + pr[16] * 5.0f;
        float cfmax = 0.5f   + pr[18] * 9.5f;
        float cfr   =          pr[20] * 0.1f;
        float cwh   =          pr[22] * 0.2f;
        float invfc   = 1.0f / fc;
        float invlpfc = 1.0f / (lp * fc);
        float ncfrcf  = -(cfr * cfmax);
        float omk0    = 1.0f - k0;
        float k0uzl   = k0 * uzl;
        float omk1    = 1.0f - k1;

        // states
        float sp = 1e-5f, mw = 1e-5f, sm = 0.5f * fc, suz = 1e-5f, slz = 1e-5f;
        // pipeline registers
        float swc = exp2f(beta * __log2f(sm * invfc));   // sw entering step 0
        float rech = 0.0f, exc = 0.0f;                   // S2 outputs (cur)
        float rech_b = 0.0f, exc_b = 0.0f;               // S2 outputs (prev)
        float rt_p = 0.0f, pet_p = 0.0f;                 // S1 out / forcing
        float qprev = 0.0f;

        auto S1 = [&](float p, float tc) -> float {      // snow stage, step i
            float dt   = tc - tt;
            float msn  = fmaxf(cfmax * dt, 0.0f);
            float mrf  = fmaxf(ncfrcf * dt, 0.0f);
            float rain = (dt >= 0.0f) ? p : 0.0f;
            float snow = p - rain;
            float sp1  = sp + snow;
            float melt = fminf(msn, sp1);
            float mw2  = mw + melt;
            float sp2  = sp1 - melt;
            float refr = fminf(mrf, mw2);
            float mw3  = mw2 - refr;
            sp = sp2 + refr;
            float mw4  = fminf(mw3, cwh * sp);
            float tosoil = mw3 - mw4;
            mw = mw4;
            return rain + tosoil;
        };
        auto S2 = [&](float rt, float pet) {             // soil stage, step i-1
            float omsw = 1.0f - swc;
            float sm1  = fmaf(rt, omsw, sm);
            rech = rt * swc;
            exc  = fmaxf(sm1 - fc, 0.0f);
            float sm2  = fminf(sm1, fc);
            float etk  = fmaf(-invlpfc, pet, 1.0f);
            sm = fmaxf(fmaxf(sm2 * etk, sm2 - pet), 1e-5f);
            swc = exp2f(beta * __log2f(sm * invfc));     // for next iter
        };
        auto S3 = [&](float rb, float ebx) -> float {    // zones stage, step i-2
            float suz1 = suz + rb + ebx;
            float suz2 = fmaxf(suz1 - perc, 0.0f);
            float pa   = suz1 - suz2;
            float suz3 = fminf(suz2, fmaf(suz2, omk0, k0uzl));
            float suzn = omk1 * suz3;
            float q01  = suz2 - suzn;
            suz = suzn;
            float slz1 = slz + pa;
            float q2   = k2 * slz1;
            slz = slz1 - q2;
            return q01 + q2;
        };
        auto full = [&](int j, bool pre, bool st) {
            if (st) {
                if (STORE4) qsim[qoff] = qprev;
                else atomicAdd(&qsim[qoff], 0.25f * qprev);
                qoff += GG;
            }
            float p = pb[j], tc = tb[j], pet = eb[j];
            if (pre) {
                pb[j] = x[xoff]; tb[j] = x[xoff + 1]; eb[j] = x[xoff + 2];
                xoff += 3 * GG;
            }
            float qv = S3(rech_b, exc_b);
            S2(rt_p, pet_p);
            float rt = S1(p, tc);
            rech_b = rech; exc_b = exc;
            rt_p = rt; pet_p = pet;
            qprev = qv;
        };

        // ---- peeled chunk 0: warm the pipeline ----
        {   // j = 0: S1(0) only
            float p = pb[0], tc = tb[0], pet = eb[0];
            pb[0] = x[xoff]; tb[0] = x[xoff + 1]; eb[0] = x[xoff + 2];
            xoff += 3 * GG;
            rt_p = S1(p, tc); pet_p = pet;
        }
        {   // j = 1: S2(0), S1(1)
            float p = pb[1], tc = tb[1], pet = eb[1];
            pb[1] = x[xoff]; tb[1] = x[xoff + 1]; eb[1] = x[xoff + 2];
            xoff += 3 * GG;
            S2(rt_p, pet_p);
            rech_b = rech; exc_b = exc;
            rt_p = S1(p, tc); pet_p = pet;
        }
        full(2, true, false);                       // j = 2: first S3 -> q(0)
#pragma unroll
        for (int j = 3; j < PD; ++j) full(j, true, true);
        // ---- main chunks 1 .. SS/PD-2 (prefetching) ----
        for (int c = 1; c < SS / PD - 1; ++c) {
#pragma unroll
            for (int j = 0; j < PD; ++j) full(j, true, true);
        }
        // ---- last chunk (no prefetch) ----
#pragma unroll
        for (int j = 0; j < PD; ++j) full(j, false, true);
        // ---- drain: q(SS-3), q(SS-2), q(SS-1) ----
        if (STORE4) { qsim[qoff] = qprev; qoff += GG; }
        else { atomicAdd(&qsim[qoff], 0.25f * qprev); qoff += GG; }
        S2(rt_p, pet_p);                            // step SS-1
        float qv = S3(rech_b, exc_b);               // step SS-2
        if (STORE4) { qsim[qoff] = qv; qoff += GG; }
        else { atomicAdd(&qsim[qoff], 0.25f * qv); qoff += GG; }
        float qf = S3(rech, exc);                   // step SS-1
        if (STORE4) qsim[qoff] = qf;
        else atomicAdd(&qsim[qoff], 0.25f * qf);
    } else {
        // ---- EXP-HYDRO parameters (descale + derived constants) ----
        const float* pe = pr + 24;
        float f    =           pe[0]  * 0.1f;
        float smax = 100.0f  + pe[2]  * 1400.0f;
        float qmax = 10.0f   + pe[4]  * 40.0f;
        float df   =           pe[6]  * 5.0f;
        float tmax =           pe[8]  * 3.0f;
        float tmin = -3.0f   + pe[10] * 3.0f;
        float invsmax = 1.0f / smax;
        float fl = f * 1.44269504f;              // f * log2(e)
        float c0 = __log2f(qmax) - fl * smax;    // fold qmax into exponent

        float s0 = 1e-5f, s1 = 0.5f * smax;
        float prr_p = 0.0f, mlt_p = 0.0f, pet_p = 0.0f;
        float qprev = 0.0f;

        auto S1e = [&](float p, float tc) {          // snow stage, step i
            float mdf = df * fmaxf(tc - tmax, 0.0f);
            float ps  = (tc <= tmin) ? p : 0.0f;
            float prr = p - ps;
            float mlt = fminf(s0, mdf);
            s0 = fmaxf(s0 - mdf, 0.0f) + ps;
            prr_p = prr; mlt_p = mlt;
        };
        auto S2e = [&](float prr, float mlt, float pet) -> float {  // step i-1
            float etk = fmaxf(fmaf(-invsmax, pet, 1.0f), 0.0f);
            float s1a = s1 + prr + mlt;
            float qspill = fmaxf(s1a - smax, 0.0f);
            float s1b = fminf(s1a, smax);
            float s1c = s1b * etk;
            float qb  = fminf(exp2f(fmaf(fl, s1c, c0)), s1c);
            s1 = s1c - qb;
            return qspill + qb;
        };
        auto full = [&](int j, bool pre, bool st) {
            if (st) {
                if (STORE4) qsim[qoff] = qprev;
                else atomicAdd(&qsim[qoff], 0.25f * qprev);
                qoff += GG;
            }
            float p = pb[j], tc = tb[j], pet = eb[j];
            if (pre) {
                pb[j] = x[xoff]; tb[j] = x[xoff + 1]; eb[j] = x[xoff + 2];
                xoff += 3 * GG;
            }
            float prr = prr_p, mlt = mlt_p, peto = pet_p;
            S1e(p, tc);                              // overwrites prr_p/mlt_p
            float qv = S2e(prr, mlt, peto);
            pet_p = pet;
            qprev = qv;
        };

        // ---- peeled chunk 0 ----
        {   // j = 0: S1e(0) only
            float p = pb[0], tc = tb[0], pet = eb[0];
            pb[0] = x[xoff]; tb[0] = x[xoff + 1]; eb[0] = x[xoff + 2];
            xoff += 3 * GG;
            S1e(p, tc); pet_p = pet;
        }
        full(1, true, false);                        // j = 1: q(0) computed
#pragma unroll
        for (int j = 2; j < PD; ++j) full(j, true, true);
        for (int c = 1; c < SS / PD - 1; ++c) {
#pragma unroll
            for (int j = 0; j < PD; ++j) full(j, true, true);
        }
#pragma unroll
        for (int j = 0; j < PD; ++j) full(j, false, true);
        // ---- drain: q(SS-2), q(SS-1) ----
        if (STORE4) { qsim[qoff] = qprev; qoff += GG; }
        else { atomicAdd(&qsim[qoff], 0.25f * qprev); qoff += GG; }
        float qf = S2e(prr_p, mlt_p, pet_p);         // step SS-1
        if (STORE4) qsim[qoff] = qf;
        else atomicAdd(&qsim[qoff], 0.25f * qf);
    }
}

// ---------------------------------------------------------------------------
// UH weights: one thread per g, 15 normalized gamma-UH weights once (0.25
// folded). gammaln cancels: w[k] ∝ exp((aa-1)ln(k+.5)-(k+.5)/th).
// ---------------------------------------------------------------------------
__global__ __launch_bounds__(256) void uh_weights(const float* __restrict__ raw,
                                                  float* __restrict__ wbuf) {
    int g = blockIdx.x * 256 + threadIdx.x;
    if (g >= GG) return;
    float a = raw[(size_t)g * 38 + 36] * 2.9f;
    float b = raw[(size_t)g * 38 + 37] * 6.5f;
    float aa = fmaxf(a, 0.0f) + 0.1f;
    float th = fmaxf(b, 0.0f) + 0.5f;
    float am1 = aa - 1.0f;
    float invth = 1.0f / th;

    const float logt[LENF] = {
        -0.69314718f, 0.40546511f, 0.91629073f, 1.25276297f, 1.50407740f,
         1.70474809f, 1.87180218f, 2.01490302f, 2.14006616f, 2.25129180f,
         2.35137526f, 2.44234704f, 2.52572864f, 2.60268969f, 2.67414865f };

    float w[LENF];
    float s = 0.0f;
#pragma unroll
    for (int k = 0; k < LENF; ++k) {
        float tk = (float)k + 0.5f;
        w[k] = expf(am1 * logt[k] - tk * invth);
        s += w[k];
    }
    float scale = 0.25f / s;
#pragma unroll
    for (int k = 0; k < LENF; ++k)
        wbuf[(size_t)k * GG + g] = w[k] * scale;
}

// ---------------------------------------------------------------------------
// Routing kernel, t-tiled: each thread owns one g and TT consecutive t's.
// WPRE: weights preloaded from wbuf (scale folded). NB = #qsim slices summed.
// ---------------------------------------------------------------------------
template<int NB, bool WPRE>
__global__ __launch_bounds__(256) void hydro_route(const float* __restrict__ qsim,
                                                   const float* __restrict__ raw,
                                                   const float* __restrict__ wbuf,
                                                   float* __restrict__ out) {
    int idx = blockIdx.x * 256 + threadIdx.x;
    if (idx >= GG * (SS / TT)) return;
    int g = idx % GG;          // g fast -> coalesced
    int c = idx / GG;
    int t0 = c * TT;

    float w[LENF];
    float scale;
    if (WPRE) {
#pragma unroll
        for (int k = 0; k < LENF; ++k)
            w[k] = wbuf[(size_t)k * GG + g];
        scale = 1.0f;
    } else {
        float a = raw[(size_t)g * 38 + 36] * 2.9f;
        float b = raw[(size_t)g * 38 + 37] * 6.5f;
        float aa = fmaxf(a, 0.0f) + 0.1f;
        float th = fmaxf(b, 0.0f) + 0.5f;
        float am1 = aa - 1.0f;
        float invth = 1.0f / th;
        const float logt[LENF] = {
            -0.69314718f, 0.40546511f, 0.91629073f, 1.25276297f, 1.50407740f,
             1.70474809f, 1.87180218f, 2.01490302f, 2.14006616f, 2.25129180f,
             2.35137526f, 2.44234704f, 2.52572864f, 2.60268969f, 2.67414865f };
        float s = 0.0f;
#pragma unroll
        for (int k = 0; k < LENF; ++k) {
            float tk = (float)k + 0.5f;
            w[k] = expf(am1 * logt[k] - tk * invth);
            s += w[k];
        }
        scale = (NB == 4 ? 0.25f : 1.0f) / s;
    }

    // load qsim[t0-14 .. t0+TT-1] (zeros before t=0), summing NB slices
    float v[TT + LENF - 1];
#pragma unroll
    for (int i = 0; i < TT + LENF - 1; ++i) {
        int tp = t0 - (LENF - 1) + i;
        float sv = 0.0f;
        if (tp >= 0) {
            const float* qb = qsim + (size_t)tp * GG + g;
            sv = qb[0];
            if (NB == 4) sv += qb[QN] + qb[2 * QN] + qb[3 * QN];
        }
        v[i] = sv;
    }
#pragma unroll
    for (int j = 0; j < TT; ++j) {
        float acc = 0.0f;
#pragma unroll
        for (int k = 0; k < LENF; ++k)
            acc += w[k] * v[j + (LENF - 1) - k];
        out[(size_t)(t0 + j) * GG + g] = (WPRE ? acc : acc * scale);
    }
}

// ---------------------------------------------------------------------------
extern "C" void kernel_launch(void* const* d_in, const int* in_sizes, int n_in,
                              void* d_out, int out_size, void* d_ws, size_t ws_size,
                              hipStream_t stream) {
    const float* x   = (const float*)d_in[0];   // (730, 4000, 3) f32
    const float* raw = (const float*)d_in[1];   // (4000, 38) f32
    float* out  = (float*)d_out;                // (730, 4000) f32
    float* qsim = (float*)d_ws;

    const size_t slices4 = 4 * QN * sizeof(float);
    const size_t wbytes  = (size_t)LENF * GG * sizeof(float);
    int rblocks = (GG * (SS / TT) + 255) / 256;
    int sblocks = (4 * GPAD) / 64;

    if (ws_size >= slices4 + wbytes) {
        float* wbuf = qsim + 4 * QN;
        hydro_scan<true><<<sblocks, 64, 0, stream>>>(x, raw, qsim);
        uh_weights<<<(GG + 255) / 256, 256, 0, stream>>>(raw, wbuf);
        hydro_route<4, true><<<rblocks, 256, 0, stream>>>(qsim, raw, wbuf, out);
    } else {
        hipMemsetAsync(qsim, 0, QN * sizeof(float), stream);
        hydro_scan<false><<<sblocks, 64, 0, stream>>>(x, raw, qsim);
        hydro_route<1, false><<<rblocks, 256, 0, stream>>>(qsim, raw, nullptr, out);
    }
}